// Round 5
// baseline (3294.340 us; speedup 1.0000x reference)
//
#include <hip/hip_runtime.h>

typedef unsigned short u16;
typedef unsigned int u32;
typedef __bf16 bfx8 __attribute__((ext_vector_type(8)));
typedef float f32x4 __attribute__((ext_vector_type(4)));

constexpr int BB = 64;     // batch
constexpr int TT = 64;     // time
constexpr int EE = 2048;   // x feature
constexpr int DD = 4096;   // deter
constexpr int GG = 8;      // groups
constexpr int H3 = 3 * DD;       // 12288
constexpr int CH = H3 / GG;      // 1536
constexpr float EPSf = 1e-4f;

static __device__ __forceinline__ u16 f2bf(float f) {
  u32 u = __builtin_bit_cast(u32, f);
  u32 r = (u + 0x7fffu + ((u >> 16) & 1u)) >> 16;
  return (u16)r;
}

// ---------------- prepass kernels ----------------

__global__ void __launch_bounds__(256) k_f2b(const float* __restrict__ in,
                                             u16* __restrict__ out, int n4) {
  int i = blockIdx.x * 256 + threadIdx.x;
  int stride = gridDim.x * 256;
  for (; i < n4; i += stride) {
    float4 v = ((const float4*)in)[i];
    uint2 o;
    o.x = (u32)f2bf(v.x) | ((u32)f2bf(v.y) << 16);
    o.y = (u32)f2bf(v.z) | ((u32)f2bf(v.w) << 16);
    ((uint2*)out)[i] = o;
  }
}

__global__ void __launch_bounds__(256) k_initdet(const float* __restrict__ d0,
                                                 float* __restrict__ dF,
                                                 u16* __restrict__ dB, int n4) {
  int i = blockIdx.x * 256 + threadIdx.x;
  if (i < n4) {
    float4 v = ((const float4*)d0)[i];
    ((float4*)dF)[i] = v;
    uint2 o;
    o.x = (u32)f2bf(v.x) | ((u32)f2bf(v.y) << 16);
    o.y = (u32)f2bf(v.z) | ((u32)f2bf(v.w) << 16);
    ((uint2*)dB)[i] = o;
  }
}

// in [R][C] f32 -> out [C][R] bf16  (batched over blockIdx.z)
__global__ void __launch_bounds__(256) k_transpose_f2b(const float* __restrict__ in,
                                                       u16* __restrict__ out,
                                                       int R, int C) {
  __shared__ float tile[32][33];
  size_t base = (size_t)blockIdx.z * R * C;
  in += base; out += base;
  int tx = threadIdx.x & 31, ty = threadIdx.x >> 5;
  int r0 = blockIdx.y * 32, c0 = blockIdx.x * 32;
#pragma unroll
  for (int i = 0; i < 4; i++) {
    int rr = ty * 4 + i;
    tile[rr][tx] = in[(size_t)(r0 + rr) * C + (c0 + tx)];
  }
  __syncthreads();
#pragma unroll
  for (int i = 0; i < 4; i++) {
    int cc = ty * 4 + i;
    out[(size_t)(c0 + cc) * R + (r0 + tx)] = f2bf(tile[tx][cc]);
  }
}

// ---------------- GEMM for P1 (Xproj): A[m][k] bf16 x B[n][k] bf16 -> C f32 ----------------

template<int BM, int BN, int WR, int WC>
__global__ void __launch_bounds__(256) k_gemm(
    const u16* __restrict__ A, int lda,
    const u16* __restrict__ B, int ldb,
    float* __restrict__ C, int ldc,
    const float* __restrict__ bias,
    int K) {
  constexpr int BK = 64, LS = BK + 8;
  constexpr int WTM = BM / WR, WTN = BN / WC, MF = WTM / 16, NF = WTN / 16;
  __shared__ u16 As[BM * LS];
  __shared__ u16 Bs[BN * LS];
  const int tid = threadIdx.x;
  const int m0 = blockIdx.y * BM, n0 = blockIdx.x * BN;
  const int w = tid >> 6, lane = tid & 63;
  const int wr = w / WC, wc = w % WC;
  const int lr = lane & 15, lk = (lane >> 4) * 8;

  f32x4 acc[MF][NF] = {};

  for (int kt = 0; kt < K; kt += BK) {
#pragma unroll
    for (int c = tid; c < BM * 8; c += 256) {
      int row = c >> 3, cc = c & 7;
      *(uint4*)&As[row * LS + cc * 8] =
          *(const uint4*)(A + (size_t)(m0 + row) * lda + kt + cc * 8);
    }
#pragma unroll
    for (int c = tid; c < BN * 8; c += 256) {
      int row = c >> 3, cc = c & 7;
      *(uint4*)&Bs[row * LS + cc * 8] =
          *(const uint4*)(B + (size_t)(n0 + row) * ldb + kt + cc * 8);
    }
    __syncthreads();
#pragma unroll
    for (int kk = 0; kk < BK; kk += 32) {
      bfx8 av[MF], bv[NF];
#pragma unroll
      for (int mi = 0; mi < MF; mi++)
        av[mi] = *(const bfx8*)&As[(wr * WTM + mi * 16 + lr) * LS + kk + lk];
#pragma unroll
      for (int ni = 0; ni < NF; ni++)
        bv[ni] = *(const bfx8*)&Bs[(wc * WTN + ni * 16 + lr) * LS + kk + lk];
#pragma unroll
      for (int mi = 0; mi < MF; mi++)
#pragma unroll
        for (int ni = 0; ni < NF; ni++)
          acc[mi][ni] = __builtin_amdgcn_mfma_f32_16x16x32_bf16(av[mi], bv[ni], acc[mi][ni], 0, 0, 0);
    }
    __syncthreads();
  }

  const int rq = (lane >> 4) * 4;
#pragma unroll
  for (int mi = 0; mi < MF; mi++) {
#pragma unroll
    for (int ni = 0; ni < NF; ni++) {
      int n = n0 + wc * WTN + ni * 16 + lr;
      float bias_v = bias ? bias[n] : 0.f;
#pragma unroll
      for (int r = 0; r < 4; r++) {
        int m = m0 + wr * WTM + mi * 16 + rq + r;
        C[(size_t)m * ldc + n] = acc[mi][ni][r] + bias_v;
      }
    }
  }
}

// ---------------- scan kernels ----------------
// kA': preact = dB @ W1 + Xproj_t; fused per-(ntile,row) sumsq partials.
// grid 64 (n-tiles), 512 thr (8 waves: 4 m-strips x 2 n-halves), full K=4096, BK=128,
// LDS dbuf + depth-1 register prefetch, ONE barrier per K-iter.
constexpr int LSA = 136;                 // 128 + 8 bf16 pad (keeps 16B align)
constexpr int ABUF = 64 * LSA;           // elems per LDS buffer

__global__ void __launch_bounds__(512) kA(const u16* __restrict__ dB,
                                          const u16* __restrict__ WT,
                                          const float* __restrict__ Xproj,
                                          float* __restrict__ preact,
                                          float* __restrict__ rowsq,
                                          int t) {
  __shared__ u16 As[2 * ABUF];
  __shared__ u16 Bs[2 * ABUF];
  const int tid = threadIdx.x;
  const int n0 = blockIdx.x * 64;
  const int w = tid >> 6, lane = tid & 63;
  const int wr = w >> 1, wc = w & 1;
  const int lr = lane & 15, lk = (lane >> 4) * 8, rq = (lane >> 4) * 4;
  // staging chunks: c in [0,1024): row=c>>4, slot=c&15 (16B). thread owns c=tid, c+512.
  const int r0s = tid >> 4, s0 = (tid & 15) * 8;          // chunk tid
  const int r1s = (tid + 512) >> 4, s1 = s0;               // chunk tid+512 (same slot bits)
  const u16* Ag0 = dB + (size_t)r0s * DD + s0;
  const u16* Ag1 = dB + (size_t)r1s * DD + s1;
  const u16* Bg0 = WT + (size_t)(n0 + r0s) * (DD + EE) + s0;
  const u16* Bg1 = WT + (size_t)(n0 + r1s) * (DD + EE) + s1;
  const int d0 = r0s * LSA + s0, d1 = r1s * LSA + s1;

  f32x4 acc[2] = {};

  uint4 ra0 = *(const uint4*)(Ag0);
  uint4 ra1 = *(const uint4*)(Ag1);
  uint4 rb0 = *(const uint4*)(Bg0);
  uint4 rb1 = *(const uint4*)(Bg1);

  for (int kt = 0; kt < 32; ++kt) {
    const int p = kt & 1;
    u16* ab = As + p * ABUF;
    u16* bb = Bs + p * ABUF;
    *(uint4*)&ab[d0] = ra0;
    *(uint4*)&ab[d1] = ra1;
    *(uint4*)&bb[d0] = rb0;
    *(uint4*)&bb[d1] = rb1;
    __syncthreads();
    if (kt < 31) {
      const int ko = (kt + 1) * 128;
      ra0 = *(const uint4*)(Ag0 + ko);
      ra1 = *(const uint4*)(Ag1 + ko);
      rb0 = *(const uint4*)(Bg0 + ko);
      rb1 = *(const uint4*)(Bg1 + ko);
    }
#pragma unroll
    for (int kk = 0; kk < 128; kk += 32) {
      bfx8 av = *(const bfx8*)&ab[(wr * 16 + lr) * LSA + kk + lk];
#pragma unroll
      for (int ni = 0; ni < 2; ni++) {
        bfx8 bv = *(const bfx8*)&bb[(wc * 32 + ni * 16 + lr) * LSA + kk + lk];
        acc[ni] = __builtin_amdgcn_mfma_f32_16x16x32_bf16(av, bv, acc[ni], 0, 0, 0);
      }
    }
    __syncthreads();
  }

  // epilogue: add Xproj, write preact, reduce per-row sumsq
  float sq[4] = {0.f, 0.f, 0.f, 0.f};
#pragma unroll
  for (int ni = 0; ni < 2; ni++) {
#pragma unroll
    for (int r = 0; r < 4; r++) {
      const int row = wr * 16 + rq + r;
      const int col = n0 + wc * 32 + ni * 16 + lr;
      const float v = acc[ni][r] + Xproj[((size_t)row * TT + t) * DD + col];
      preact[(size_t)row * DD + col] = v;
      sq[r] += v * v;
    }
  }
#pragma unroll
  for (int o = 1; o < 16; o <<= 1) {
#pragma unroll
    for (int r = 0; r < 4; r++) sq[r] += __shfl_xor(sq[r], o);
  }
  if (lr == 0) {
#pragma unroll
    for (int r = 0; r < 4; r++)
      rowsq[(size_t)blockIdx.x * 128 + wc * 64 + wr * 16 + rq + r] = sq[r];
  }
}

// kC': row-RMS finish + silu + bf16-cvt fused into A staging; block GEMM2; zsq partials.
// grid 192 (64 z-cols each), 256 thr.
__global__ void __launch_bounds__(256) kC(const float* __restrict__ preact,
                                          const float* __restrict__ rowsq,
                                          const float* __restrict__ scale_in,
                                          const u16* __restrict__ WbT,
                                          const float* __restrict__ b_blk,
                                          float* __restrict__ zbuf,
                                          float* __restrict__ zsq) {
  constexpr int LS = 72;
  __shared__ u16 As[64 * LS];
  __shared__ u16 Bs[64 * LS];
  __shared__ float red[64][5];
  __shared__ float rsL[64];
  const int tid = threadIdx.x;
  const int wg = blockIdx.x;
  const int n0g = wg * 64;
  const int g = wg / 24, nl = n0g - g * CH;
  const int w = tid >> 6, lane = tid & 63;
  const int lr = lane & 15, lk = (lane >> 4) * 8, rq = (lane >> 4) * 4;

  // ---- row sumsq reduce: rowsq[64 nt][2][64 rows] ----
  {
    const int r = tid >> 2, p = tid & 3;
    float s = 0.f;
#pragma unroll
    for (int i = 0; i < 16; i++) {
      const int nt = p * 16 + i;
      s += rowsq[(size_t)nt * 128 + r] + rowsq[(size_t)nt * 128 + 64 + r];
    }
    red[r][p] = s;
  }
  __syncthreads();
  if (tid < 64)
    rsL[tid] = rsqrtf((red[tid][0] + red[tid][1] + red[tid][2] + red[tid][3]) / (float)DD + EPSf);
  __syncthreads();

  // ---- GEMM2 with fused A prep ----
  const int arow = tid >> 2, acb = (tid & 3) * 16;
  const float* Ap = preact + (size_t)arow * DD + g * 512 + acb;
  const float* Sp = scale_in + g * 512 + acb;
  const u16* Brow = WbT + ((size_t)g * CH + nl + (tid >> 2)) * 512 + (tid & 3) * 8;
  const int bdst = (tid >> 2) * LS + (tid & 3) * 8;

  f32x4 acc[4] = {};
  for (int kt = 0; kt < 512; kt += 64) {
    // A: read f32 preact, apply rms*scale + silu, cvt bf16, stage
    const float rr = rsL[arow];
    float4 f0 = *(const float4*)(Ap + kt);
    float4 f1 = *(const float4*)(Ap + kt + 4);
    float4 f2 = *(const float4*)(Ap + kt + 8);
    float4 f3 = *(const float4*)(Ap + kt + 12);
    float4 s0 = *(const float4*)(Sp + kt);
    float4 s1 = *(const float4*)(Sp + kt + 4);
    float4 s2 = *(const float4*)(Sp + kt + 8);
    float4 s3 = *(const float4*)(Sp + kt + 12);
    float yv[16];
    yv[0] = f0.x * rr * s0.x; yv[1] = f0.y * rr * s0.y; yv[2] = f0.z * rr * s0.z; yv[3] = f0.w * rr * s0.w;
    yv[4] = f1.x * rr * s1.x; yv[5] = f1.y * rr * s1.y; yv[6] = f1.z * rr * s1.z; yv[7] = f1.w * rr * s1.w;
    yv[8] = f2.x * rr * s2.x; yv[9] = f2.y * rr * s2.y; yv[10] = f2.z * rr * s2.z; yv[11] = f2.w * rr * s2.w;
    yv[12] = f3.x * rr * s3.x; yv[13] = f3.y * rr * s3.y; yv[14] = f3.z * rr * s3.z; yv[15] = f3.w * rr * s3.w;
    uint4 o0, o1;
    u32* po0 = (u32*)&o0; u32* po1 = (u32*)&o1;
#pragma unroll
    for (int j = 0; j < 4; j++) {
      float a = yv[2 * j], b = yv[2 * j + 1];
      a = a / (1.f + __expf(-a)); b = b / (1.f + __expf(-b));
      po0[j] = (u32)f2bf(a) | ((u32)f2bf(b) << 16);
      float c = yv[8 + 2 * j], d = yv[8 + 2 * j + 1];
      c = c / (1.f + __expf(-c)); d = d / (1.f + __expf(-d));
      po1[j] = (u32)f2bf(c) | ((u32)f2bf(d) << 16);
    }
    *(uint4*)&As[arow * LS + acb] = o0;
    *(uint4*)&As[arow * LS + acb + 8] = o1;
    // B: bf16 copy
    *(uint4*)&Bs[bdst] = *(const uint4*)(Brow + kt);
    *(uint4*)&Bs[bdst + 32] = *(const uint4*)(Brow + kt + 32);
    __syncthreads();
#pragma unroll
    for (int kk = 0; kk < 64; kk += 32) {
      bfx8 av = *(const bfx8*)&As[(w * 16 + lr) * LS + kk + lk];
#pragma unroll
      for (int ni = 0; ni < 4; ni++) {
        bfx8 bv = *(const bfx8*)&Bs[(ni * 16 + lr) * LS + kk + lk];
        acc[ni] = __builtin_amdgcn_mfma_f32_16x16x32_bf16(av, bv, acc[ni], 0, 0, 0);
      }
    }
    __syncthreads();
  }

  // epilogue: bias, zbuf write, zsq partials
  float sq[4] = {0.f, 0.f, 0.f, 0.f};
#pragma unroll
  for (int ni = 0; ni < 4; ni++) {
    const int n = n0g + ni * 16 + lr;
    const float bias_v = b_blk[n];
#pragma unroll
    for (int r = 0; r < 4; r++) {
      const float zv = acc[ni][r] + bias_v;
      zbuf[(size_t)(w * 16 + rq + r) * H3 + n] = zv;
      sq[r] += zv * zv;
    }
  }
#pragma unroll
  for (int o = 1; o < 16; o <<= 1) {
#pragma unroll
    for (int r = 0; r < 4; r++) sq[r] += __shfl_xor(sq[r], o);
  }
  if (lr == 0) {
#pragma unroll
    for (int r = 0; r < 4; r++) zsq[(size_t)wg * 64 + w * 16 + rq + r] = sq[r];
  }
}

// kD: block-rms + gates + deter update + out write   grid 256 (= 64 b x 4 col-slices)
__global__ void __launch_bounds__(256) kD(const float* __restrict__ zbuf,
                                          const float* __restrict__ zsq,
                                          const float* __restrict__ sblk,
                                          float* __restrict__ dF,
                                          u16* __restrict__ dB,
                                          float* __restrict__ out, int t) {
  const int wg = blockIdx.x, tid = threadIdx.x;
  const int b = wg >> 2, s = wg & 3;
  __shared__ float sred[8];
  if (tid < 8) {
    float ssq = 0.f;
    const int j0 = tid * 24;
#pragma unroll
    for (int j = 0; j < 24; j++) ssq += zsq[(size_t)(j0 + j) * 64 + b];
    sred[tid] = rsqrtf(ssq / (float)CH + EPSf);
  }
  __syncthreads();
  const int d0 = s * 1024 + tid * 4;
  const float* zr = zbuf + (size_t)b * H3;
  float4 z0 = *(const float4*)(zr + d0);
  float4 z1 = *(const float4*)(zr + DD + d0);
  float4 z2 = *(const float4*)(zr + 2 * DD + d0);
  float4 dold = *(const float4*)(dF + (size_t)b * DD + d0);
  const float rsA = sred[d0 / CH];
  const float rsB = sred[(DD + d0) / CH];
  const float rsC = sred[(2 * DD + d0) / CH];
  float dn[4];
  const float* z0p = (const float*)&z0;
  const float* z1p = (const float*)&z1;
  const float* z2p = (const float*)&z2;
  const float* dop = (const float*)&dold;
#pragma unroll
  for (int e = 0; e < 4; e++) {
    const int dd = d0 + e;
    const float a0 = z0p[e] * rsA * sblk[dd];
    const float a1 = z1p[e] * rsB * sblk[DD + dd];
    const float a2 = z2p[e] * rsC * sblk[2 * DD + dd];
    const float reset = 1.f / (1.f + __expf(-a0));
    const float cand = tanhf(reset * a1);
    const float upd = 1.f / (1.f + __expf(-(a2 - 1.f)));
    dn[e] = upd * cand + (1.f - upd) * dop[e];
  }
  *(float4*)(dF + (size_t)b * DD + d0) = make_float4(dn[0], dn[1], dn[2], dn[3]);
  uint2 o;
  o.x = (u32)f2bf(dn[0]) | ((u32)f2bf(dn[1]) << 16);
  o.y = (u32)f2bf(dn[2]) | ((u32)f2bf(dn[3]) << 16);
  *(uint2*)(dB + (size_t)b * DD + d0) = o;
  *(float4*)(out + ((size_t)b * TT + t) * DD + d0) = make_float4(dn[0], dn[1], dn[2], dn[3]);
}

// ---------------- host ----------------

extern "C" void kernel_launch(void* const* d_in, const int* in_sizes, int n_in,
                              void* d_out, int out_size, void* d_ws, size_t ws_size,
                              hipStream_t stream) {
  (void)in_sizes; (void)n_in; (void)out_size; (void)ws_size;
  const float* x         = (const float*)d_in[0];  // [B,T,E]
  const float* deter0    = (const float*)d_in[1];  // [B,D]
  const float* W_in      = (const float*)d_in[2];  // [D+E, D]
  const float* b_in      = (const float*)d_in[3];  // [D]
  const float* scale_in  = (const float*)d_in[4];  // [D]
  const float* W_blk     = (const float*)d_in[5];  // [G, D/G, 3D/G]
  const float* b_blk     = (const float*)d_in[6];  // [3D]
  const float* scale_blk = (const float*)d_in[7];  // [G, 3D/G]
  float* out = (float*)d_out;

  char* ws = (char*)d_ws;
  size_t off = 0;
  auto alloc = [&](size_t bytes) -> void* {
    void* p = ws + off;
    off += (bytes + 255) & ~(size_t)255;
    return p;
  };
  u16*   WT    = (u16*)alloc((size_t)DD * (DD + EE) * 2);       // 50.3 MB
  u16*   WbT   = (u16*)alloc((size_t)GG * CH * (DD / GG) * 2);  // 12.6 MB
  float* Xproj = (float*)alloc((size_t)BB * TT * DD * 4);       // 64 MB
  float* dF    = (float*)alloc((size_t)BB * DD * 4);            // 1 MB
  u16*   dB    = (u16*)alloc((size_t)BB * DD * 2);              // 0.5 MB
  // scratch region: xbf (prepass/P1 only) aliases scan-only buffers
  char* scratch = (char*)alloc((size_t)BB * TT * EE * 2);       // 16.8 MB
  u16*   xbf  = (u16*)scratch;
  float* preact = (float*)scratch;                              // 1 MB
  size_t o2 = (size_t)BB * DD * 4;
  float* rowsq = (float*)(scratch + o2);                        // 32 KB
  o2 += (size_t)64 * 128 * 4;
  float* zbuf = (float*)(scratch + o2);                         // 3 MB
  o2 += (size_t)BB * H3 * 4;
  float* zsq  = (float*)(scratch + o2);                         // 48 KB

  // prepass: convert & transpose
  k_f2b<<<dim3(2048), dim3(256), 0, stream>>>(x, xbf, BB * TT * EE / 4);
  k_transpose_f2b<<<dim3(DD / 32, (DD + EE) / 32, 1), dim3(256), 0, stream>>>(W_in, WT, DD + EE, DD);
  k_transpose_f2b<<<dim3(CH / 32, (DD / GG) / 32, GG), dim3(256), 0, stream>>>(W_blk, WbT, DD / GG, CH);
  k_initdet<<<dim3(BB * DD / 4 / 256), dim3(256), 0, stream>>>(deter0, dF, dB, BB * DD / 4);

  // P1: Xproj = x @ W2 + b_in   (M=4096, K=2048, N=4096); W2T rows at WT col-offset DD
  k_gemm<128, 128, 2, 2><<<dim3(DD / 128, BB * TT / 128, 1), dim3(256), 0, stream>>>(
      xbf, EE,
      WT + DD, DD + EE,
      Xproj, DD,
      b_in,
      EE);

  for (int t = 0; t < TT; t++) {
    kA<<<dim3(64), dim3(512), 0, stream>>>(dB, WT, Xproj, preact, rowsq, t);
    kC<<<dim3(192), dim3(256), 0, stream>>>(preact, rowsq, scale_in, WbT, b_blk, zbuf, zsq);
    kD<<<dim3(256), dim3(256), 0, stream>>>(zbuf, zsq, scale_blk, dF, dB, out, t);
  }
}

// Round 6
// 1999.321 us; speedup vs baseline: 1.6477x; 1.6477x over previous
//
#include <hip/hip_runtime.h>

typedef unsigned short u16;
typedef unsigned int u32;
typedef __bf16 bfx8 __attribute__((ext_vector_type(8)));
typedef float f32x4 __attribute__((ext_vector_type(4)));

constexpr int BB = 64;     // batch
constexpr int TT = 64;     // time
constexpr int EE = 2048;   // x feature
constexpr int DD = 4096;   // deter
constexpr int GG = 8;      // groups
constexpr int H3 = 3 * DD;       // 12288
constexpr int CH = H3 / GG;      // 1536
constexpr float EPSf = 1e-4f;

static __device__ __forceinline__ u16 f2bf(float f) {
  u32 u = __builtin_bit_cast(u32, f);
  u32 r = (u + 0x7fffu + ((u >> 16) & 1u)) >> 16;
  return (u16)r;
}
static __device__ __forceinline__ float bf2f(u16 h) {
  return __builtin_bit_cast(float, (u32)h << 16);
}

// ---------------- prepass kernels ----------------

__global__ void __launch_bounds__(256) k_f2b(const float* __restrict__ in,
                                             u16* __restrict__ out, int n4) {
  int i = blockIdx.x * 256 + threadIdx.x;
  int stride = gridDim.x * 256;
  for (; i < n4; i += stride) {
    float4 v = ((const float4*)in)[i];
    uint2 o;
    o.x = (u32)f2bf(v.x) | ((u32)f2bf(v.y) << 16);
    o.y = (u32)f2bf(v.z) | ((u32)f2bf(v.w) << 16);
    ((uint2*)out)[i] = o;
  }
}

__global__ void __launch_bounds__(256) k_initdet(const float* __restrict__ d0,
                                                 float* __restrict__ dF,
                                                 u16* __restrict__ dB, int n4) {
  int i = blockIdx.x * 256 + threadIdx.x;
  if (i < n4) {
    float4 v = ((const float4*)d0)[i];
    ((float4*)dF)[i] = v;
    uint2 o;
    o.x = (u32)f2bf(v.x) | ((u32)f2bf(v.y) << 16);
    o.y = (u32)f2bf(v.z) | ((u32)f2bf(v.w) << 16);
    ((uint2*)dB)[i] = o;
  }
}

// in [R][C] f32 -> out [C][R] bf16  (batched over blockIdx.z)
__global__ void __launch_bounds__(256) k_transpose_f2b(const float* __restrict__ in,
                                                       u16* __restrict__ out,
                                                       int R, int C) {
  __shared__ float tile[32][33];
  size_t base = (size_t)blockIdx.z * R * C;
  in += base; out += base;
  int tx = threadIdx.x & 31, ty = threadIdx.x >> 5;
  int r0 = blockIdx.y * 32, c0 = blockIdx.x * 32;
#pragma unroll
  for (int i = 0; i < 4; i++) {
    int rr = ty * 4 + i;
    tile[rr][tx] = in[(size_t)(r0 + rr) * C + (c0 + tx)];
  }
  __syncthreads();
#pragma unroll
  for (int i = 0; i < 4; i++) {
    int cc = ty * 4 + i;
    out[(size_t)(c0 + cc) * R + (r0 + tx)] = f2bf(tile[tx][cc]);
  }
}

// ---------------- P1: Xproj = x @ W2 + b_in -> bf16 ----------------
// 128x128 tile, BK=64, 4 waves (2x2), dbuf + reg prefetch, 1 barrier/iter.
constexpr int P1_LS = 72;           // 64 + 8 pad
constexpr int P1_BUF = 128 * P1_LS; // elems per buffer

__global__ void __launch_bounds__(256) k_p1(const u16* __restrict__ A,  // [4096][2048]
                                            const u16* __restrict__ B,  // [4096][6144] (W2T cols at +0)
                                            const float* __restrict__ bias,
                                            u16* __restrict__ C) {      // [4096][4096] bf16
  __shared__ u16 As[2 * P1_BUF];
  __shared__ u16 Bs[2 * P1_BUF];
  const int tid = threadIdx.x;
  const int m0 = blockIdx.y * 128, n0 = blockIdx.x * 128;
  const int w = tid >> 6, lane = tid & 63;
  const int wr = w >> 1, wc = w & 1;
  const int lr = lane & 15, lk = (lane >> 4) * 8, rq = (lane >> 4) * 4;
  const int srow = tid >> 3, scol = (tid & 7) * 8;  // + 32*i rows
  const u16* Ag = A + (size_t)(m0 + srow) * EE + scol;
  const u16* Bg = B + (size_t)(n0 + srow) * (DD + EE) + scol;

  f32x4 acc[4][4] = {};
  uint4 ra[4], rb[4];
#pragma unroll
  for (int i = 0; i < 4; i++) {
    ra[i] = *(const uint4*)(Ag + (size_t)32 * i * EE);
    rb[i] = *(const uint4*)(Bg + (size_t)32 * i * (DD + EE));
  }

  for (int kt = 0; kt < 32; ++kt) {
    const int p = kt & 1;
    u16* ab = As + p * P1_BUF;
    u16* bb = Bs + p * P1_BUF;
#pragma unroll
    for (int i = 0; i < 4; i++) {
      *(uint4*)&ab[(srow + 32 * i) * P1_LS + scol] = ra[i];
      *(uint4*)&bb[(srow + 32 * i) * P1_LS + scol] = rb[i];
    }
    __syncthreads();
    if (kt < 31) {
      const int ko = (kt + 1) * 64;
#pragma unroll
      for (int i = 0; i < 4; i++) {
        ra[i] = *(const uint4*)(Ag + (size_t)32 * i * EE + ko);
        rb[i] = *(const uint4*)(Bg + (size_t)32 * i * (DD + EE) + ko);
      }
    }
#pragma unroll
    for (int kk = 0; kk < 64; kk += 32) {
      bfx8 av[4], bv[4];
#pragma unroll
      for (int mi = 0; mi < 4; mi++)
        av[mi] = *(const bfx8*)&ab[(wr * 64 + mi * 16 + lr) * P1_LS + kk + lk];
#pragma unroll
      for (int ni = 0; ni < 4; ni++)
        bv[ni] = *(const bfx8*)&bb[(wc * 64 + ni * 16 + lr) * P1_LS + kk + lk];
#pragma unroll
      for (int mi = 0; mi < 4; mi++)
#pragma unroll
        for (int ni = 0; ni < 4; ni++)
          acc[mi][ni] = __builtin_amdgcn_mfma_f32_16x16x32_bf16(av[mi], bv[ni], acc[mi][ni], 0, 0, 0);
    }
  }

#pragma unroll
  for (int mi = 0; mi < 4; mi++) {
#pragma unroll
    for (int ni = 0; ni < 4; ni++) {
      const int n = n0 + wc * 64 + ni * 16 + lr;
      const float bias_v = bias[n];
#pragma unroll
      for (int r = 0; r < 4; r++) {
        const int m = m0 + wr * 64 + mi * 16 + rq + r;
        C[(size_t)m * DD + n] = f2bf(acc[mi][ni][r] + bias_v);
      }
    }
  }
}

// ---------------- scan kernels ----------------
// kA: part[kc] = dB @ W1[:, kc*1024 .. +1024]
// grid (64 n-tiles, 4 kc), 512 thr (8 waves: 4 m-strips x 2 n-halves), BK=128,
// LDS dbuf + reg prefetch, ONE barrier per K-iter.
constexpr int LSA = 136;                 // 128 + 8 pad
constexpr int ABUF = 64 * LSA;

__global__ void __launch_bounds__(512) kA(const u16* __restrict__ dB,
                                          const u16* __restrict__ WT,
                                          float* __restrict__ part) {
  __shared__ u16 As[2 * ABUF];
  __shared__ u16 Bs[2 * ABUF];
  const int tid = threadIdx.x;
  const int n0 = blockIdx.x * 64;
  const int k0 = blockIdx.y * 1024;
  const int w = tid >> 6, lane = tid & 63;
  const int wr = w >> 1, wc = w & 1;
  const int lr = lane & 15, lk = (lane >> 4) * 8, rq = (lane >> 4) * 4;
  const int r0s = tid >> 4, s0 = (tid & 15) * 8;   // chunk tid: rows 0..31
  const int r1s = r0s + 32;                         // chunk tid+512: rows 32..63
  const u16* Ag0 = dB + (size_t)r0s * DD + k0 + s0;
  const u16* Ag1 = dB + (size_t)r1s * DD + k0 + s0;
  const u16* Bg0 = WT + (size_t)(n0 + r0s) * (DD + EE) + k0 + s0;
  const u16* Bg1 = WT + (size_t)(n0 + r1s) * (DD + EE) + k0 + s0;
  const int d0 = r0s * LSA + s0, d1 = r1s * LSA + s0;

  f32x4 acc[2] = {};
  uint4 ra0 = *(const uint4*)(Ag0);
  uint4 ra1 = *(const uint4*)(Ag1);
  uint4 rb0 = *(const uint4*)(Bg0);
  uint4 rb1 = *(const uint4*)(Bg1);

  for (int kt = 0; kt < 8; ++kt) {
    const int p = kt & 1;
    u16* ab = As + p * ABUF;
    u16* bb = Bs + p * ABUF;
    *(uint4*)&ab[d0] = ra0;
    *(uint4*)&ab[d1] = ra1;
    *(uint4*)&bb[d0] = rb0;
    *(uint4*)&bb[d1] = rb1;
    __syncthreads();
    if (kt < 7) {
      const int ko = (kt + 1) * 128;
      ra0 = *(const uint4*)(Ag0 + ko);
      ra1 = *(const uint4*)(Ag1 + ko);
      rb0 = *(const uint4*)(Bg0 + ko);
      rb1 = *(const uint4*)(Bg1 + ko);
    }
#pragma unroll
    for (int kk = 0; kk < 128; kk += 32) {
      bfx8 av = *(const bfx8*)&ab[(wr * 16 + lr) * LSA + kk + lk];
#pragma unroll
      for (int ni = 0; ni < 2; ni++) {
        bfx8 bv = *(const bfx8*)&bb[(wc * 32 + ni * 16 + lr) * LSA + kk + lk];
        acc[ni] = __builtin_amdgcn_mfma_f32_16x16x32_bf16(av, bv, acc[ni], 0, 0, 0);
      }
    }
  }

  float* Pp = part + (size_t)blockIdx.y * BB * DD;
#pragma unroll
  for (int ni = 0; ni < 2; ni++)
#pragma unroll
    for (int r = 0; r < 4; r++)
      Pp[(size_t)(wr * 16 + rq + r) * DD + n0 + wc * 32 + ni * 16 + lr] = acc[ni][r];
}

// kB: y = silu(rms(sum_k part + Xproj_t) * scale_in) -> bf16   grid 64
__global__ void __launch_bounds__(256) kB(const float* __restrict__ part,
                                          const u16* __restrict__ Xproj,
                                          const float* __restrict__ scale_in,
                                          u16* __restrict__ ybf, int t) {
  const int b = blockIdx.x, tid = threadIdx.x;
  const int w = tid >> 6, lane = tid & 63;
  __shared__ float sred[4];
  const u16* xp = Xproj + ((size_t)b * TT + t) * DD + tid * 16;
  const float* pb = part + (size_t)b * DD + tid * 16;
  float v[16];
  uint4 x0 = *(const uint4*)(xp);
  uint4 x1 = *(const uint4*)(xp + 8);
#pragma unroll
  for (int j = 0; j < 8; j++) v[j] = bf2f(((const u16*)&x0)[j]);
#pragma unroll
  for (int j = 0; j < 8; j++) v[8 + j] = bf2f(((const u16*)&x1)[j]);
#pragma unroll
  for (int kc = 0; kc < 4; kc++) {
    const float* p = pb + (size_t)kc * BB * DD;
#pragma unroll
    for (int j4 = 0; j4 < 4; j4++) {
      float4 q = *(const float4*)(p + j4 * 4);
      v[j4 * 4 + 0] += q.x; v[j4 * 4 + 1] += q.y;
      v[j4 * 4 + 2] += q.z; v[j4 * 4 + 3] += q.w;
    }
  }
  float ss = 0.f;
#pragma unroll
  for (int j = 0; j < 16; j++) ss += v[j] * v[j];
#pragma unroll
  for (int o = 32; o > 0; o >>= 1) ss += __shfl_down(ss, o);
  if (lane == 0) sred[w] = ss;
  __syncthreads();
  const float r = rsqrtf((sred[0] + sred[1] + sred[2] + sred[3]) / (float)DD + EPSf);
  const float* sc = scale_in + tid * 16;
  uint2 o0, o1;
  u32* po = (u32*)&o0;
#pragma unroll
  for (int j = 0; j < 4; j++) {
    float a = v[2 * j] * r * sc[2 * j];
    float bq = v[2 * j + 1] * r * sc[2 * j + 1];
    a = a / (1.f + __expf(-a)); bq = bq / (1.f + __expf(-bq));
    po[j & 1] = (u32)f2bf(a) | ((u32)f2bf(bq) << 16);
    if (j == 1) *(uint2*)(ybf + (size_t)b * DD + tid * 16) = o0;
  }
  *(uint2*)(ybf + (size_t)b * DD + tid * 16 + 4) = o0;  // placeholder overwritten below
  // redo cleanly for all 16 to avoid the tangle above:
  u32 pk[8];
#pragma unroll
  for (int j = 0; j < 8; j++) {
    float a = v[2 * j] * r * sc[2 * j];
    float bq = v[2 * j + 1] * r * sc[2 * j + 1];
    a = a / (1.f + __expf(-a)); bq = bq / (1.f + __expf(-bq));
    pk[j] = (u32)f2bf(a) | ((u32)f2bf(bq) << 16);
  }
  uint4 w0 = make_uint4(pk[0], pk[1], pk[2], pk[3]);
  uint4 w1 = make_uint4(pk[4], pk[5], pk[6], pk[7]);
  *(uint4*)(ybf + (size_t)b * DD + tid * 16) = w0;
  *(uint4*)(ybf + (size_t)b * DD + tid * 16 + 8) = w1;
}

// kC: z = blockdiag(y @ Wblk) + b_blk -> zbuf f32; fused per-row sumsq -> zsq[192][64]
// grid 192, 256 thr, BK=64, dbuf + reg prefetch, 1 barrier/iter.
constexpr int LSC2 = 72;
constexpr int CBUF = 64 * LSC2;

__global__ void __launch_bounds__(256) kC(const u16* __restrict__ ybf,
                                          const u16* __restrict__ WbT,
                                          const float* __restrict__ b_blk,
                                          float* __restrict__ zbuf,
                                          float* __restrict__ zsq) {
  __shared__ u16 As[2 * CBUF];
  __shared__ u16 Bs[2 * CBUF];
  const int tid = threadIdx.x;
  const int wg = blockIdx.x;
  const int n0g = wg * 64;
  const int g = n0g / CH, nl = n0g % CH;
  const int w = tid >> 6, lane = tid & 63;
  const int lr = lane & 15, lk = (lane >> 4) * 8, rq = (lane >> 4) * 4;
  const int srow = tid >> 2, sc = (tid & 3) * 8;
  const u16* Arow = ybf + (size_t)srow * DD + g * (DD / GG) + sc;
  const u16* Brow = WbT + ((size_t)g * CH + nl + srow) * (DD / GG) + sc;
  const int dA = srow * LSC2 + sc;

  f32x4 acc[4] = {};
  uint4 ra0 = *(const uint4*)(Arow);
  uint4 ra1 = *(const uint4*)(Arow + 32);
  uint4 rb0 = *(const uint4*)(Brow);
  uint4 rb1 = *(const uint4*)(Brow + 32);

  for (int kt = 0; kt < 8; ++kt) {
    const int p = kt & 1;
    u16* ab = As + p * CBUF;
    u16* bb = Bs + p * CBUF;
    *(uint4*)&ab[dA] = ra0;
    *(uint4*)&ab[dA + 32] = ra1;
    *(uint4*)&bb[dA] = rb0;
    *(uint4*)&bb[dA + 32] = rb1;
    __syncthreads();
    if (kt < 7) {
      const int ko = (kt + 1) * 64;
      ra0 = *(const uint4*)(Arow + ko);
      ra1 = *(const uint4*)(Arow + ko + 32);
      rb0 = *(const uint4*)(Brow + ko);
      rb1 = *(const uint4*)(Brow + ko + 32);
    }
#pragma unroll
    for (int kk = 0; kk < 64; kk += 32) {
      bfx8 av = *(const bfx8*)&ab[(w * 16 + lr) * LSC2 + kk + lk];
#pragma unroll
      for (int ni = 0; ni < 4; ni++) {
        bfx8 bv = *(const bfx8*)&bb[(ni * 16 + lr) * LSC2 + kk + lk];
        acc[ni] = __builtin_amdgcn_mfma_f32_16x16x32_bf16(av, bv, acc[ni], 0, 0, 0);
      }
    }
  }

  float sq[4] = {0.f, 0.f, 0.f, 0.f};
#pragma unroll
  for (int ni = 0; ni < 4; ni++) {
    const int n = n0g + ni * 16 + lr;
    const float bias_v = b_blk[n];
#pragma unroll
    for (int r = 0; r < 4; r++) {
      const float zv = acc[ni][r] + bias_v;
      zbuf[(size_t)(w * 16 + rq + r) * H3 + n] = zv;
      sq[r] += zv * zv;
    }
  }
#pragma unroll
  for (int o = 1; o < 16; o <<= 1) {
#pragma unroll
    for (int r = 0; r < 4; r++) sq[r] += __shfl_xor(sq[r], o);
  }
  if (lr == 0) {
#pragma unroll
    for (int r = 0; r < 4; r++) zsq[(size_t)wg * 64 + w * 16 + rq + r] = sq[r];
  }
}

// kD: block-rms + gates + deter update + out write   grid 256 (= 64 b x 4 col-slices)
__global__ void __launch_bounds__(256) kD(const float* __restrict__ zbuf,
                                          const float* __restrict__ zsq,
                                          const float* __restrict__ sblk,
                                          float* __restrict__ dF,
                                          u16* __restrict__ dB,
                                          float* __restrict__ out, int t) {
  const int wg = blockIdx.x, tid = threadIdx.x;
  const int b = wg >> 2, s = wg & 3;
  __shared__ float sred[8];
  if (tid < 8) {
    float ssq = 0.f;
    const int j0 = tid * 24;
#pragma unroll
    for (int j = 0; j < 24; j++) ssq += zsq[(size_t)(j0 + j) * 64 + b];
    sred[tid] = rsqrtf(ssq / (float)CH + EPSf);
  }
  __syncthreads();
  const int d0 = s * 1024 + tid * 4;
  const float* zr = zbuf + (size_t)b * H3;
  float4 z0 = *(const float4*)(zr + d0);
  float4 z1 = *(const float4*)(zr + DD + d0);
  float4 z2 = *(const float4*)(zr + 2 * DD + d0);
  float4 dold = *(const float4*)(dF + (size_t)b * DD + d0);
  const float rsA = sred[d0 / CH];
  const float rsB = sred[(DD + d0) / CH];
  const float rsC = sred[(2 * DD + d0) / CH];
  float dn[4];
  const float* z0p = (const float*)&z0;
  const float* z1p = (const float*)&z1;
  const float* z2p = (const float*)&z2;
  const float* dop = (const float*)&dold;
#pragma unroll
  for (int e = 0; e < 4; e++) {
    const int dd = d0 + e;
    const float a0 = z0p[e] * rsA * sblk[dd];
    const float a1 = z1p[e] * rsB * sblk[DD + dd];
    const float a2 = z2p[e] * rsC * sblk[2 * DD + dd];
    const float reset = 1.f / (1.f + __expf(-a0));
    const float cand = tanhf(reset * a1);
    const float upd = 1.f / (1.f + __expf(-(a2 - 1.f)));
    dn[e] = upd * cand + (1.f - upd) * dop[e];
  }
  *(float4*)(dF + (size_t)b * DD + d0) = make_float4(dn[0], dn[1], dn[2], dn[3]);
  uint2 o;
  o.x = (u32)f2bf(dn[0]) | ((u32)f2bf(dn[1]) << 16);
  o.y = (u32)f2bf(dn[2]) | ((u32)f2bf(dn[3]) << 16);
  *(uint2*)(dB + (size_t)b * DD + d0) = o;
  *(float4*)(out + ((size_t)b * TT + t) * DD + d0) = make_float4(dn[0], dn[1], dn[2], dn[3]);
}

// ---------------- host ----------------

extern "C" void kernel_launch(void* const* d_in, const int* in_sizes, int n_in,
                              void* d_out, int out_size, void* d_ws, size_t ws_size,
                              hipStream_t stream) {
  (void)in_sizes; (void)n_in; (void)out_size; (void)ws_size;
  const float* x         = (const float*)d_in[0];  // [B,T,E]
  const float* deter0    = (const float*)d_in[1];  // [B,D]
  const float* W_in      = (const float*)d_in[2];  // [D+E, D]
  const float* b_in      = (const float*)d_in[3];  // [D]
  const float* scale_in  = (const float*)d_in[4];  // [D]
  const float* W_blk     = (const float*)d_in[5];  // [G, D/G, 3D/G]
  const float* b_blk     = (const float*)d_in[6];  // [3D]
  const float* scale_blk = (const float*)d_in[7];  // [G, 3D/G]
  float* out = (float*)d_out;

  char* ws = (char*)d_ws;
  size_t off = 0;
  auto alloc = [&](size_t bytes) -> void* {
    void* p = ws + off;
    off += (bytes + 255) & ~(size_t)255;
    return p;
  };
  u16*   WT    = (u16*)alloc((size_t)DD * (DD + EE) * 2);       // 50.3 MB
  u16*   WbT   = (u16*)alloc((size_t)GG * CH * (DD / GG) * 2);  // 12.6 MB
  u16*   Xproj = (u16*)alloc((size_t)BB * TT * DD * 2);         // 32 MB (bf16)
  float* dF    = (float*)alloc((size_t)BB * DD * 4);            // 1 MB
  u16*   dB    = (u16*)alloc((size_t)BB * DD * 2);              // 0.5 MB
  // scratch region: xbf (prepass/P1 only) aliases scan-only buffers
  char* scratch = (char*)alloc((size_t)BB * TT * EE * 2);       // 16.8 MB
  u16*   xbf  = (u16*)scratch;
  float* part = (float*)scratch;                                // 4 MB (4 splits)
  size_t o2 = (size_t)4 * BB * DD * 4;
  u16*   ybf  = (u16*)(scratch + o2);                           // 0.5 MB
  o2 += (size_t)BB * DD * 2;
  float* zbuf = (float*)(scratch + o2);                         // 3 MB
  o2 += (size_t)BB * H3 * 4;
  float* zsq  = (float*)(scratch + o2);                         // 48 KB

  // prepass: convert & transpose
  k_f2b<<<dim3(2048), dim3(256), 0, stream>>>(x, xbf, BB * TT * EE / 4);
  k_transpose_f2b<<<dim3(DD / 32, (DD + EE) / 32, 1), dim3(256), 0, stream>>>(W_in, WT, DD + EE, DD);
  k_transpose_f2b<<<dim3(CH / 32, (DD / GG) / 32, GG), dim3(256), 0, stream>>>(W_blk, WbT, DD / GG, CH);
  k_initdet<<<dim3(BB * DD / 4 / 256), dim3(256), 0, stream>>>(deter0, dF, dB, BB * DD / 4);

  // P1: Xproj = x @ W2 + b_in -> bf16   (M=4096, K=2048, N=4096)
  k_p1<<<dim3(DD / 128, BB * TT / 128), dim3(256), 0, stream>>>(
      xbf, WT + DD, b_in, Xproj);

  for (int t = 0; t < TT; t++) {
    kA<<<dim3(64, 4), dim3(512), 0, stream>>>(dB, WT, part);
    kB<<<dim3(BB), dim3(256), 0, stream>>>(part, Xproj, scale_in, ybf, t);
    kC<<<dim3(192), dim3(256), 0, stream>>>(ybf, WbT, b_blk, zbuf, zsq);
    kD<<<dim3(256), dim3(256), 0, stream>>>(zbuf, zsq, scale_blk, dF, dB, out, t);
  }
}